// Round 1
// baseline (891.848 us; speedup 1.0000x reference)
//
#include <hip/hip_runtime.h>

typedef unsigned short u16;
typedef short short8 __attribute__((ext_vector_type(8)));
typedef float f32x4 __attribute__((ext_vector_type(4)));

#define MM 18464   // B*N rows
#define CC 768
#define NTOK 577

__device__ __forceinline__ u16 f2bf(float f) {
    unsigned u = __builtin_bit_cast(unsigned, f);
    u += 0x7fffu + ((u >> 16) & 1u);
    return (u16)(u >> 16);
}

__device__ __forceinline__ void gload16(const void* g, void* lds) {
    __builtin_amdgcn_global_load_lds(
        (const __attribute__((address_space(1))) unsigned*)g,
        (__attribute__((address_space(3))) unsigned*)lds,
        16, 0, 0);
}

// ---------------- weight convert + transpose: src[K][N] f32 -> dst[N][K] bf16 ----------------
__global__ __launch_bounds__(256) void convT(const float* __restrict__ src,
                                             u16* __restrict__ dst, int K, int N) {
    __shared__ float tile[32][33];
    const int k0 = blockIdx.x * 32, n0 = blockIdx.y * 32;
    const int tx = threadIdx.x & 31, ty = threadIdx.x >> 5;  // 32 x 8
#pragma unroll
    for (int i = 0; i < 32; i += 8)
        tile[ty + i][tx] = src[(size_t)(k0 + ty + i) * N + n0 + tx];
    __syncthreads();
#pragma unroll
    for (int i = 0; i < 32; i += 8)
        dst[(size_t)(n0 + ty + i) * K + k0 + tx] = f2bf(tile[tx][ty + i]);
}

// ---------------- layernorm: f32 row[768] -> bf16 ----------------
__global__ __launch_bounds__(192) void ln_k(const float* __restrict__ x,
                                            const float* __restrict__ g,
                                            const float* __restrict__ bt,
                                            u16* __restrict__ out) {
    const int row = blockIdx.x, t = threadIdx.x;
    const float4 v = reinterpret_cast<const float4*>(x + (size_t)row * 768)[t];
    float s = v.x + v.y + v.z + v.w;
    float s2 = v.x * v.x + v.y * v.y + v.z * v.z + v.w * v.w;
#pragma unroll
    for (int off = 32; off > 0; off >>= 1) {
        s += __shfl_down(s, off);
        s2 += __shfl_down(s2, off);
    }
    __shared__ float red[6];
    if ((t & 63) == 0) { red[t >> 6] = s; red[3 + (t >> 6)] = s2; }
    __syncthreads();
    const float S = red[0] + red[1] + red[2];
    const float S2 = red[3] + red[4] + red[5];
    const float mu = S * (1.f / 768.f);
    const float var = S2 * (1.f / 768.f) - mu * mu;
    const float rs = rsqrtf(var + 1e-5f);
    const float4 gg = reinterpret_cast<const float4*>(g)[t];
    const float4 bb = reinterpret_cast<const float4*>(bt)[t];
    ushort4 r;
    r.x = f2bf((v.x - mu) * rs * gg.x + bb.x);
    r.y = f2bf((v.y - mu) * rs * gg.y + bb.y);
    r.z = f2bf((v.z - mu) * rs * gg.z + bb.z);
    r.w = f2bf((v.w - mu) * rs * gg.w + bb.w);
    reinterpret_cast<ushort4*>(out + (size_t)row * 768)[t] = r;
}

// ---------------- GEMM: C[M][N] = A[M][K](bf16) * BT[N][K](bf16)^T + bias, epilogue per MODE ----
// MODE 0: out bf16 = acc + bias                      (qkv)
// MODE 1: out f32  = acc + bias + resid              (proj -> x1)
// MODE 2: out bf16 = gelu(acc + bias)                (fc1)
// MODE 3: out f32  = acc + bias + resid              (fc2 -> d_out)
template <int MODE>
__global__ __launch_bounds__(256) void gemm_k(const u16* __restrict__ A,
                                              const u16* __restrict__ BT,
                                              const float* __restrict__ bias,
                                              const float* __restrict__ resid,
                                              void* __restrict__ outp,
                                              int M, int N, int K) {
    __shared__ u16 As[128 * 32];
    __shared__ u16 Bs[128 * 32];
    const int t = threadIdx.x;
    const int wid = t >> 6, lane = t & 63;
    const int l15 = lane & 15, lg = lane >> 4;
    const int m0 = blockIdx.x * 128, n0 = blockIdx.y * 128;
    const int wr = wid >> 1, wc = wid & 1;

    f32x4 acc[4][4] = {};

    const int srow = t >> 2;        // 0..63
    const int sk = (t & 3) * 8;
    const size_t a0 = (size_t)min(m0 + srow, M - 1) * K + sk;
    const size_t a1 = (size_t)min(m0 + srow + 64, M - 1) * K + sk;
    const size_t b0 = (size_t)(n0 + srow) * K + sk;
    const size_t b1 = (size_t)(n0 + srow + 64) * K + sk;
    u16* ldsA = As + wid * 512;     // wave-uniform dest, +lane*16B implicit
    u16* ldsB = Bs + wid * 512;

    for (int k0 = 0; k0 < K; k0 += 32) {
        gload16(A + a0 + k0, ldsA);
        gload16(A + a1 + k0, ldsA + 2048);
        gload16(BT + b0 + k0, ldsB);
        gload16(BT + b1 + k0, ldsB + 2048);
        __syncthreads();
        short8 af[4], bf[4];
#pragma unroll
        for (int fr = 0; fr < 4; ++fr)
            af[fr] = *(const short8*)&As[(wr * 64 + fr * 16 + l15) * 32 + lg * 8];
#pragma unroll
        for (int fc = 0; fc < 4; ++fc)
            bf[fc] = *(const short8*)&Bs[(wc * 64 + fc * 16 + l15) * 32 + lg * 8];
#pragma unroll
        for (int fr = 0; fr < 4; ++fr)
#pragma unroll
            for (int fc = 0; fc < 4; ++fc)
                acc[fr][fc] = __builtin_amdgcn_mfma_f32_16x16x32_bf16(
                    af[fr], bf[fc], acc[fr][fc], 0, 0, 0);
        __syncthreads();
    }

    float bcol[4];
#pragma unroll
    for (int fc = 0; fc < 4; ++fc) bcol[fc] = bias[n0 + wc * 64 + fc * 16 + l15];
#pragma unroll
    for (int fr = 0; fr < 4; ++fr) {
#pragma unroll
        for (int reg = 0; reg < 4; ++reg) {
            const int row = m0 + wr * 64 + fr * 16 + lg * 4 + reg;
            if (row < M) {
#pragma unroll
                for (int fc = 0; fc < 4; ++fc) {
                    const int col = n0 + wc * 64 + fc * 16 + l15;
                    float v = acc[fr][fc][reg] + bcol[fc];
                    if (MODE == 2) v = 0.5f * v * (1.0f + erff(v * 0.70710678118f));
                    if (MODE == 1 || MODE == 3) v += resid[(size_t)row * N + col];
                    if (MODE == 0 || MODE == 2)
                        ((u16*)outp)[(size_t)row * N + col] = f2bf(v);
                    else
                        ((float*)outp)[(size_t)row * N + col] = v;
                }
            }
        }
    }
}

// ---------------- flash attention over qkv[M][2304] bf16, out o[M][768] bf16 ----------------
__global__ __launch_bounds__(256) void attn_k(const u16* __restrict__ qkv,
                                              u16* __restrict__ o) {
    const int qt = blockIdx.x;   // 0..9
    const int bh = blockIdx.y;   // 0..383
    const int b = bh / 12, h = bh % 12;
    const int t = threadIdx.x, wid = t >> 6, lane = t & 63;
    const int l15 = lane & 15, lg = lane >> 4;
    const size_t base = ((size_t)b * NTOK) * 2304 + (size_t)h * 64;

    __shared__ u16 Ks[64 * 64], Vs[64 * 64], Ps[64 * 64];

    int qrow = qt * 64 + wid * 16 + l15;
    qrow = min(qrow, NTOK - 1);
    const u16* Qp = qkv + base + (size_t)qrow * 2304 + lg * 8;
    const short8 qf0 = *(const short8*)(Qp);
    const short8 qf1 = *(const short8*)(Qp + 32);

    f32x4 oacc[4] = {};
    float m_run[4], l_run[4];
#pragma unroll
    for (int j = 0; j < 4; ++j) { m_run[j] = -1e30f; l_run[j] = 0.f; }

    const int srow = t >> 3;      // 0..31
    const int sd = (t & 7) * 8;
    u16* ldsK = Ks + wid * 512;
    u16* ldsV = Vs + wid * 512;

    for (int kt = 0; kt < 10; ++kt) {
        const int n0t = kt * 64;
        const int r0 = min(n0t + srow, NTOK - 1);
        const int r1 = min(n0t + srow + 32, NTOK - 1);
        gload16(qkv + base + 768 + (size_t)r0 * 2304 + sd, ldsK);
        gload16(qkv + base + 768 + (size_t)r1 * 2304 + sd, ldsK + 2048);
        gload16(qkv + base + 1536 + (size_t)r0 * 2304 + sd, ldsV);
        gload16(qkv + base + 1536 + (size_t)r1 * 2304 + sd, ldsV + 2048);
        __syncthreads();

        // S = Q K^T
        f32x4 s[4];
#pragma unroll
        for (int fc = 0; fc < 4; ++fc) {
            f32x4 a_ = {};
            const short8 kf0 = *(const short8*)&Ks[(fc * 16 + l15) * 64 + lg * 8];
            const short8 kf1 = *(const short8*)&Ks[(fc * 16 + l15) * 64 + 32 + lg * 8];
            a_ = __builtin_amdgcn_mfma_f32_16x16x32_bf16(qf0, kf0, a_, 0, 0, 0);
            a_ = __builtin_amdgcn_mfma_f32_16x16x32_bf16(qf1, kf1, a_, 0, 0, 0);
            s[fc] = a_;
        }
#pragma unroll
        for (int fc = 0; fc < 4; ++fc) {
            const bool valid = (n0t + fc * 16 + l15) < NTOK;
#pragma unroll
            for (int j = 0; j < 4; ++j)
                s[fc][j] = valid ? s[fc][j] * 0.125f : -1e30f;
        }
        // row max
        float mt[4];
#pragma unroll
        for (int j = 0; j < 4; ++j)
            mt[j] = fmaxf(fmaxf(s[0][j], s[1][j]), fmaxf(s[2][j], s[3][j]));
#pragma unroll
        for (int off = 1; off < 16; off <<= 1)
#pragma unroll
            for (int j = 0; j < 4; ++j) mt[j] = fmaxf(mt[j], __shfl_xor(mt[j], off));
        float mn[4], alpha[4];
#pragma unroll
        for (int j = 0; j < 4; ++j) {
            mn[j] = fmaxf(m_run[j], mt[j]);
            alpha[j] = __expf(m_run[j] - mn[j]);
            m_run[j] = mn[j];
        }
        float lsum[4] = {0.f, 0.f, 0.f, 0.f};
#pragma unroll
        for (int fc = 0; fc < 4; ++fc)
#pragma unroll
            for (int j = 0; j < 4; ++j) {
                const float p = __expf(s[fc][j] - mn[j]);
                s[fc][j] = p;
                lsum[j] += p;
            }
#pragma unroll
        for (int off = 1; off < 16; off <<= 1)
#pragma unroll
            for (int j = 0; j < 4; ++j) lsum[j] += __shfl_xor(lsum[j], off);
#pragma unroll
        for (int j = 0; j < 4; ++j) l_run[j] = l_run[j] * alpha[j] + lsum[j];
#pragma unroll
        for (int fc = 0; fc < 4; ++fc)
#pragma unroll
            for (int j = 0; j < 4; ++j) oacc[fc][j] *= alpha[j];

        // write P (bf16) to per-wave LDS slice, D-layout -> A-layout transpose
#pragma unroll
        for (int fc = 0; fc < 4; ++fc)
#pragma unroll
            for (int j = 0; j < 4; ++j)
                Ps[(wid * 16 + lg * 4 + j) * 64 + fc * 16 + l15] = f2bf(s[fc][j]);
        asm volatile("s_waitcnt lgkmcnt(0)" ::: "memory");

        // O += P V
#pragma unroll
        for (int c = 0; c < 2; ++c) {
            const short8 pf = *(const short8*)&Ps[(wid * 16 + l15) * 64 + c * 32 + lg * 8];
#pragma unroll
            for (int fc = 0; fc < 4; ++fc) {
                short8 vf;
#pragma unroll
                for (int j = 0; j < 8; ++j)
                    vf[j] = (short)Vs[(c * 32 + lg * 8 + j) * 64 + fc * 16 + l15];
                oacc[fc] = __builtin_amdgcn_mfma_f32_16x16x32_bf16(pf, vf, oacc[fc], 0, 0, 0);
            }
        }
        __syncthreads();
    }

#pragma unroll
    for (int j = 0; j < 4; ++j) {
        const int row = qt * 64 + wid * 16 + lg * 4 + j;
        if (row < NTOK) {
            const float inv = 1.0f / l_run[j];
#pragma unroll
            for (int fc = 0; fc < 4; ++fc)
                o[((size_t)(b * NTOK + row)) * 768 + h * 64 + fc * 16 + l15] =
                    f2bf(oacc[fc][j] * inv);
        }
    }
}

extern "C" void kernel_launch(void* const* d_in, const int* in_sizes, int n_in,
                              void* d_out, int out_size, void* d_ws, size_t ws_size,
                              hipStream_t stream) {
    const float* x      = (const float*)d_in[0];
    const float* ln1_g  = (const float*)d_in[1];
    const float* ln1_b  = (const float*)d_in[2];
    const float* qkv_w  = (const float*)d_in[3];
    const float* qkv_b  = (const float*)d_in[4];
    const float* proj_w = (const float*)d_in[5];
    const float* proj_b = (const float*)d_in[6];
    const float* ln2_g  = (const float*)d_in[7];
    const float* ln2_b  = (const float*)d_in[8];
    const float* fc1_w  = (const float*)d_in[9];
    const float* fc1_b  = (const float*)d_in[10];
    const float* fc2_w  = (const float*)d_in[11];
    const float* fc2_b  = (const float*)d_in[12];
    float* out = (float*)d_out;

    char* ws = (char*)d_ws;
    size_t off = 0;
    u16* WQ  = (u16*)(ws + off); off += (size_t)2304 * 768 * 2;   // qkv_w^T
    u16* WP  = (u16*)(ws + off); off += (size_t)768 * 768 * 2;    // proj_w^T
    u16* W1  = (u16*)(ws + off); off += (size_t)3072 * 768 * 2;   // fc1_w^T
    u16* W2  = (u16*)(ws + off); off += (size_t)768 * 3072 * 2;   // fc2_w^T
    u16* LN1 = (u16*)(ws + off); off += (size_t)MM * 768 * 2;
    u16* QKV = (u16*)(ws + off); off += (size_t)MM * 2304 * 2;
    u16* OB  = (u16*)(ws + off); off += (size_t)MM * 768 * 2;
    float* X1 = (float*)(ws + off); off += (size_t)MM * 768 * 4;
    u16* LN2 = (u16*)(ws + off); off += (size_t)MM * 768 * 2;
    u16* HID = LN1;  // aliases LN1+QKV (28.4MB + 85.1MB = 113.4MB), dead by fc1

    // weights -> bf16 transposed
    convT<<<dim3(24, 72), 256, 0, stream>>>(qkv_w, WQ, 768, 2304);
    convT<<<dim3(24, 24), 256, 0, stream>>>(proj_w, WP, 768, 768);
    convT<<<dim3(24, 96), 256, 0, stream>>>(fc1_w, W1, 768, 3072);
    convT<<<dim3(96, 24), 256, 0, stream>>>(fc2_w, W2, 3072, 768);

    // MSA branch
    ln_k<<<MM, 192, 0, stream>>>(x, ln1_g, ln1_b, LN1);
    gemm_k<0><<<dim3(145, 18), 256, 0, stream>>>(LN1, WQ, qkv_b, nullptr, QKV,
                                                 MM, 2304, 768);
    attn_k<<<dim3(10, 384), 256, 0, stream>>>(QKV, OB);
    gemm_k<1><<<dim3(145, 6), 256, 0, stream>>>(OB, WP, proj_b, x, X1,
                                                MM, 768, 768);
    // MLP branch
    ln_k<<<MM, 192, 0, stream>>>(X1, ln2_g, ln2_b, LN2);
    gemm_k<2><<<dim3(145, 24), 256, 0, stream>>>(LN2, W1, fc1_b, nullptr, HID,
                                                 MM, 3072, 768);
    gemm_k<3><<<dim3(145, 6), 256, 0, stream>>>(HID, W2, fc2_b, X1, out,
                                                MM, 768, 3072);
}

// Round 2
// 849.236 us; speedup vs baseline: 1.0502x; 1.0502x over previous
//
#include <hip/hip_runtime.h>

typedef unsigned short u16;
typedef short short8 __attribute__((ext_vector_type(8)));
typedef float f32x4 __attribute__((ext_vector_type(4)));

#define MM 18464   // B*N rows
#define NTOK 577

__device__ __forceinline__ u16 f2bf(float f) {
    unsigned u = __builtin_bit_cast(unsigned, f);
    u += 0x7fffu + ((u >> 16) & 1u);
    return (u16)(u >> 16);
}

__device__ __forceinline__ void gload16(const void* g, void* lds) {
    __builtin_amdgcn_global_load_lds(
        (const __attribute__((address_space(1))) unsigned*)g,
        (__attribute__((address_space(3))) unsigned*)lds,
        16, 0, 0);
}

// bijective XCD-chunked block swizzle (m204): consecutive remapped ids share an XCD
__device__ __forceinline__ int2 xcd_swz(int gx, int gy) {
    const int nwg = gx * gy;
    const int flat = blockIdx.x + blockIdx.y * gx;
    const int q = nwg >> 3, r = nwg & 7;
    const int xcd = flat & 7, lid = flat >> 3;
    const int w = (xcd < r ? xcd * (q + 1) : r * (q + 1) + (xcd - r) * q) + lid;
    int2 o; o.x = w % gx; o.y = w / gx; return o;
}

// ---------------- weight convert + transpose: src[K][N] f32 -> dst[N][K] bf16 ----------------
__global__ __launch_bounds__(256) void convT(const float* __restrict__ src,
                                             u16* __restrict__ dst, int K, int N) {
    __shared__ float tile[32][33];
    const int k0 = blockIdx.x * 32, n0 = blockIdx.y * 32;
    const int tx = threadIdx.x & 31, ty = threadIdx.x >> 5;  // 32 x 8
#pragma unroll
    for (int i = 0; i < 32; i += 8)
        tile[ty + i][tx] = src[(size_t)(k0 + ty + i) * N + n0 + tx];
    __syncthreads();
#pragma unroll
    for (int i = 0; i < 32; i += 8)
        dst[(size_t)(n0 + ty + i) * K + k0 + tx] = f2bf(tile[tx][ty + i]);
}

// ---------------- layernorm: f32 row[768] -> bf16 ----------------
__global__ __launch_bounds__(192) void ln_k(const float* __restrict__ x,
                                            const float* __restrict__ g,
                                            const float* __restrict__ bt,
                                            u16* __restrict__ out) {
    const int row = blockIdx.x, t = threadIdx.x;
    const float4 v = reinterpret_cast<const float4*>(x + (size_t)row * 768)[t];
    float s = v.x + v.y + v.z + v.w;
    float s2 = v.x * v.x + v.y * v.y + v.z * v.z + v.w * v.w;
#pragma unroll
    for (int off = 32; off > 0; off >>= 1) {
        s += __shfl_down(s, off);
        s2 += __shfl_down(s2, off);
    }
    __shared__ float red[6];
    if ((t & 63) == 0) { red[t >> 6] = s; red[3 + (t >> 6)] = s2; }
    __syncthreads();
    const float S = red[0] + red[1] + red[2];
    const float S2 = red[3] + red[4] + red[5];
    const float mu = S * (1.f / 768.f);
    const float var = S2 * (1.f / 768.f) - mu * mu;
    const float rs = rsqrtf(var + 1e-5f);
    const float4 gg = reinterpret_cast<const float4*>(g)[t];
    const float4 bb = reinterpret_cast<const float4*>(bt)[t];
    ushort4 r;
    r.x = f2bf((v.x - mu) * rs * gg.x + bb.x);
    r.y = f2bf((v.y - mu) * rs * gg.y + bb.y);
    r.z = f2bf((v.z - mu) * rs * gg.z + bb.z);
    r.w = f2bf((v.w - mu) * rs * gg.w + bb.w);
    reinterpret_cast<ushort4*>(out + (size_t)row * 768)[t] = r;
}

// ---------------- GEMM: C[M][N] = A[M][K](bf16) * BT[N][K](bf16)^T + bias -----------------
// MODE 0: out bf16 = acc + bias                      (qkv)
// MODE 1: out f32  = acc + bias + resid              (proj -> x1)
// MODE 2: out bf16 = gelu(acc + bias)                (fc1)
// MODE 3: out f32  = acc + bias + resid              (fc2 -> d_out)
template <int MODE>
__global__ __launch_bounds__(256) void gemm_k(const u16* __restrict__ A,
                                              const u16* __restrict__ BT,
                                              const float* __restrict__ bias,
                                              const float* __restrict__ resid,
                                              void* __restrict__ outp,
                                              int M, int N, int K) {
    __shared__ u16 As[2][128 * 32];
    __shared__ u16 Bs[2][128 * 32];
    const int t = threadIdx.x;
    const int wid = t >> 6, lane = t & 63;
    const int l15 = lane & 15, lg = lane >> 4;
    const int2 sw = xcd_swz(gridDim.x, gridDim.y);
    const int m0 = sw.x * 128, n0 = sw.y * 128;
    const int wr = wid >> 1, wc = wid & 1;

    f32x4 acc[4][4] = {};

    const int srow = t >> 2;        // 0..63
    const int sk = (t & 3) * 8;
    const size_t a0 = (size_t)min(m0 + srow, M - 1) * K + sk;
    const size_t a1 = (size_t)min(m0 + srow + 64, M - 1) * K + sk;
    const size_t b0 = (size_t)(n0 + srow) * K + sk;
    const size_t b1 = (size_t)(n0 + srow + 64) * K + sk;
    const int wo = wid * 512;       // wave-uniform LDS dest (+lane*16B implicit)

    auto stage = [&](int buf, int k0) {
        gload16(A + a0 + k0, &As[buf][wo]);
        gload16(A + a1 + k0, &As[buf][wo + 2048]);
        gload16(BT + b0 + k0, &Bs[buf][wo]);
        gload16(BT + b1 + k0, &Bs[buf][wo + 2048]);
    };
    auto compute = [&](int buf) {
        short8 af[4], bfr[4];
#pragma unroll
        for (int fr = 0; fr < 4; ++fr)
            af[fr] = *(const short8*)&As[buf][(wr * 64 + fr * 16 + l15) * 32 + lg * 8];
#pragma unroll
        for (int fc = 0; fc < 4; ++fc)
            bfr[fc] = *(const short8*)&Bs[buf][(wc * 64 + fc * 16 + l15) * 32 + lg * 8];
#pragma unroll
        for (int fr = 0; fr < 4; ++fr)
#pragma unroll
            for (int fc = 0; fc < 4; ++fc)
                acc[fr][fc] = __builtin_amdgcn_mfma_f32_16x16x32_bf16(
                    af[fr], bfr[fc], acc[fr][fc], 0, 0, 0);
    };

    // 2-phase: prefetch next K-step while computing current (one drain+barrier per step)
    stage(0, 0);
    __syncthreads();
    int cur = 0;
    const int nk = K >> 5;
    for (int kt = 1; kt < nk; ++kt) {
        stage(cur ^ 1, kt * 32);
        compute(cur);
        __syncthreads();
        cur ^= 1;
    }
    compute(cur);

    float bcol[4];
#pragma unroll
    for (int fc = 0; fc < 4; ++fc) bcol[fc] = bias[n0 + wc * 64 + fc * 16 + l15];
#pragma unroll
    for (int fr = 0; fr < 4; ++fr) {
#pragma unroll
        for (int reg = 0; reg < 4; ++reg) {
            const int row = m0 + wr * 64 + fr * 16 + lg * 4 + reg;
            if (row < M) {
#pragma unroll
                for (int fc = 0; fc < 4; ++fc) {
                    const int col = n0 + wc * 64 + fc * 16 + l15;
                    float v = acc[fr][fc][reg] + bcol[fc];
                    if (MODE == 2) v = 0.5f * v * (1.0f + erff(v * 0.70710678118f));
                    if (MODE == 1 || MODE == 3) v += resid[(size_t)row * N + col];
                    if (MODE == 0 || MODE == 2)
                        ((u16*)outp)[(size_t)row * N + col] = f2bf(v);
                    else
                        ((float*)outp)[(size_t)row * N + col] = v;
                }
            }
        }
    }
}

// ---------------- flash attention over qkv[M][2304] bf16, out o[M][768] bf16 ----------------
// LDS layouts (all 16B-slot XOR-swizzled to spread banks):
//   Ks[r][d]  : slot ^= (r&7)        (staged via pre-swizzled global source)
//   VT[d][kv] : slot ^= ((d>>3)&7)   (register-staged transpose)
//   Ps[q][kv] : slot ^= (q&7)
__global__ __launch_bounds__(256) void attn_k(const u16* __restrict__ qkv,
                                              u16* __restrict__ o) {
    const int2 sw = xcd_swz(10, 384);
    const int qt = sw.x;             // 0..9
    const int bh = sw.y;             // 0..383
    const int b = bh / 12, h = bh % 12;
    const int t = threadIdx.x, wid = t >> 6, lane = t & 63;
    const int l15 = lane & 15, lg = lane >> 4;
    const size_t base = ((size_t)b * NTOK) * 2304 + (size_t)h * 64;

    __shared__ u16 Ks[64 * 64], VT[64 * 64], Ps[64 * 64];

    int qrow = qt * 64 + wid * 16 + l15;
    qrow = min(qrow, NTOK - 1);
    const u16* Qp = qkv + base + (size_t)qrow * 2304 + lg * 8;
    const short8 qf0 = *(const short8*)(Qp);
    const short8 qf1 = *(const short8*)(Qp + 32);

    f32x4 oacc[4] = {};
    float m_run[4], l_run[4];
#pragma unroll
    for (int j = 0; j < 4; ++j) { m_run[j] = -1e30f; l_run[j] = 0.f; }

    const int srow = t >> 3;               // 0..31 (kv row within half-tile)
    const int cchunk = t & 7;              // 16B chunk within 128B row
    const int ksd = (cchunk ^ (srow & 7)) * 8;   // pre-swizzled K source offset
    u16* ldsK = Ks + wid * 512;
    const int vs0 = ((srow >> 3) ^ cchunk) * 8 + (srow & 7);
    const int vs1 = (((srow >> 3) + 4) ^ cchunk) * 8 + (srow & 7);

    for (int kt = 0; kt < 10; ++kt) {
        const int n0t = kt * 64;
        const int r0 = min(n0t + srow, NTOK - 1);
        const int r1 = min(n0t + srow + 32, NTOK - 1);
        // K: async staged, source chunk XOR-swizzled so LDS slot (r,c) holds chunk c^(r&7)
        gload16(qkv + base + 768 + (size_t)r0 * 2304 + ksd, ldsK);
        gload16(qkv + base + 768 + (size_t)r1 * 2304 + ksd, ldsK + 2048);
        // V: regs -> transposed swizzled LDS
        const short8 v0 = *(const short8*)(qkv + base + 1536 + (size_t)r0 * 2304 + cchunk * 8);
        const short8 v1 = *(const short8*)(qkv + base + 1536 + (size_t)r1 * 2304 + cchunk * 8);
#pragma unroll
        for (int j = 0; j < 8; ++j) {
            VT[(cchunk * 8 + j) * 64 + vs0] = (u16)v0[j];
            VT[(cchunk * 8 + j) * 64 + vs1] = (u16)v1[j];
        }
        __syncthreads();

        // S = Q K^T
        f32x4 s[4];
#pragma unroll
        for (int fc = 0; fc < 4; ++fc) {
            const int krow = fc * 16 + l15;
            const short8 kf0 = *(const short8*)&Ks[krow * 64 + ((lg ^ (krow & 7)) * 8)];
            const short8 kf1 = *(const short8*)&Ks[krow * 64 + (((lg + 4) ^ (krow & 7)) * 8)];
            f32x4 a_ = {};
            a_ = __builtin_amdgcn_mfma_f32_16x16x32_bf16(qf0, kf0, a_, 0, 0, 0);
            a_ = __builtin_amdgcn_mfma_f32_16x16x32_bf16(qf1, kf1, a_, 0, 0, 0);
            s[fc] = a_;
        }
#pragma unroll
        for (int fc = 0; fc < 4; ++fc) {
            const bool valid = (n0t + fc * 16 + l15) < NTOK;
#pragma unroll
            for (int j = 0; j < 4; ++j)
                s[fc][j] = valid ? s[fc][j] * 0.125f : -1e30f;
        }
        // online softmax (rows live across lanes l15 within each lg group)
        float mt[4];
#pragma unroll
        for (int j = 0; j < 4; ++j)
            mt[j] = fmaxf(fmaxf(s[0][j], s[1][j]), fmaxf(s[2][j], s[3][j]));
#pragma unroll
        for (int off = 1; off < 16; off <<= 1)
#pragma unroll
            for (int j = 0; j < 4; ++j) mt[j] = fmaxf(mt[j], __shfl_xor(mt[j], off));
        float mn[4], alpha[4];
#pragma unroll
        for (int j = 0; j < 4; ++j) {
            mn[j] = fmaxf(m_run[j], mt[j]);
            alpha[j] = __expf(m_run[j] - mn[j]);
            m_run[j] = mn[j];
        }
        float lsum[4] = {0.f, 0.f, 0.f, 0.f};
#pragma unroll
        for (int fc = 0; fc < 4; ++fc)
#pragma unroll
            for (int j = 0; j < 4; ++j) {
                const float p = __expf(s[fc][j] - mn[j]);
                s[fc][j] = p;
                lsum[j] += p;
            }
#pragma unroll
        for (int off = 1; off < 16; off <<= 1)
#pragma unroll
            for (int j = 0; j < 4; ++j) lsum[j] += __shfl_xor(lsum[j], off);
#pragma unroll
        for (int j = 0; j < 4; ++j) l_run[j] = l_run[j] * alpha[j] + lsum[j];
#pragma unroll
        for (int fc = 0; fc < 4; ++fc)
#pragma unroll
            for (int j = 0; j < 4; ++j) oacc[fc][j] *= alpha[j];

        // P (bf16) -> swizzled LDS, D-layout -> A-layout transpose (wave-private rows)
#pragma unroll
        for (int fc = 0; fc < 4; ++fc)
#pragma unroll
            for (int j = 0; j < 4; ++j) {
                const int q = wid * 16 + lg * 4 + j;
                Ps[q * 64 + (((fc * 2 + (l15 >> 3)) ^ (q & 7)) * 8) + (l15 & 7)] =
                    f2bf(s[fc][j]);
            }
        asm volatile("s_waitcnt lgkmcnt(0)" ::: "memory");

        // O += P V   (both operands now vector ds_read_b128)
#pragma unroll
        for (int c = 0; c < 2; ++c) {
            const short8 pf = *(const short8*)
                &Ps[(wid * 16 + l15) * 64 + (((c * 4 + lg) ^ (l15 & 7)) * 8)];
#pragma unroll
            for (int fc = 0; fc < 4; ++fc) {
                const short8 vf = *(const short8*)
                    &VT[(fc * 16 + l15) * 64 +
                        (((c * 4 + lg) ^ (fc * 2 + (l15 >> 3))) * 8)];
                oacc[fc] = __builtin_amdgcn_mfma_f32_16x16x32_bf16(pf, vf, oacc[fc], 0, 0, 0);
            }
        }
        __syncthreads();
    }

#pragma unroll
    for (int j = 0; j < 4; ++j) {
        const int row = qt * 64 + wid * 16 + lg * 4 + j;
        if (row < NTOK) {
            const float inv = 1.0f / l_run[j];
#pragma unroll
            for (int fc = 0; fc < 4; ++fc)
                o[((size_t)(b * NTOK + row)) * 768 + h * 64 + fc * 16 + l15] =
                    f2bf(oacc[fc][j] * inv);
        }
    }
}

extern "C" void kernel_launch(void* const* d_in, const int* in_sizes, int n_in,
                              void* d_out, int out_size, void* d_ws, size_t ws_size,
                              hipStream_t stream) {
    const float* x      = (const float*)d_in[0];
    const float* ln1_g  = (const float*)d_in[1];
    const float* ln1_b  = (const float*)d_in[2];
    const float* qkv_w  = (const float*)d_in[3];
    const float* qkv_b  = (const float*)d_in[4];
    const float* proj_w = (const float*)d_in[5];
    const float* proj_b = (const float*)d_in[6];
    const float* ln2_g  = (const float*)d_in[7];
    const float* ln2_b  = (const float*)d_in[8];
    const float* fc1_w  = (const float*)d_in[9];
    const float* fc1_b  = (const float*)d_in[10];
    const float* fc2_w  = (const float*)d_in[11];
    const float* fc2_b  = (const float*)d_in[12];
    float* out = (float*)d_out;

    char* ws = (char*)d_ws;
    size_t off = 0;
    u16* WQ  = (u16*)(ws + off); off += (size_t)2304 * 768 * 2;   // qkv_w^T
    u16* WP  = (u16*)(ws + off); off += (size_t)768 * 768 * 2;    // proj_w^T
    u16* W1  = (u16*)(ws + off); off += (size_t)3072 * 768 * 2;   // fc1_w^T
    u16* W2  = (u16*)(ws + off); off += (size_t)768 * 3072 * 2;   // fc2_w^T
    u16* LN1 = (u16*)(ws + off); off += (size_t)MM * 768 * 2;
    u16* QKV = (u16*)(ws + off); off += (size_t)MM * 2304 * 2;
    u16* OB  = (u16*)(ws + off); off += (size_t)MM * 768 * 2;
    float* X1 = (float*)(ws + off); off += (size_t)MM * 768 * 4;
    u16* LN2 = (u16*)(ws + off); off += (size_t)MM * 768 * 2;
    u16* HID = LN1;  // aliases LN1+QKV (dead by fc1)

    // weights -> bf16 transposed
    convT<<<dim3(24, 72), 256, 0, stream>>>(qkv_w, WQ, 768, 2304);
    convT<<<dim3(24, 24), 256, 0, stream>>>(proj_w, WP, 768, 768);
    convT<<<dim3(24, 96), 256, 0, stream>>>(fc1_w, W1, 768, 3072);
    convT<<<dim3(96, 24), 256, 0, stream>>>(fc2_w, W2, 3072, 768);

    // MSA branch
    ln_k<<<MM, 192, 0, stream>>>(x, ln1_g, ln1_b, LN1);
    gemm_k<0><<<dim3(145, 18), 256, 0, stream>>>(LN1, WQ, qkv_b, nullptr, QKV,
                                                 MM, 2304, 768);
    attn_k<<<dim3(10, 384), 256, 0, stream>>>(QKV, OB);
    gemm_k<1><<<dim3(145, 6), 256, 0, stream>>>(OB, WP, proj_b, x, X1,
                                                MM, 768, 768);
    // MLP branch
    ln_k<<<MM, 192, 0, stream>>>(X1, ln2_g, ln2_b, LN2);
    gemm_k<2><<<dim3(145, 24), 256, 0, stream>>>(LN2, W1, fc1_b, nullptr, HID,
                                                 MM, 3072, 768);
    gemm_k<3><<<dim3(145, 6), 256, 0, stream>>>(HID, W2, fc2_b, X1, out,
                                                MM, 768, 3072);
}

// Round 3
// 749.565 us; speedup vs baseline: 1.1898x; 1.1330x over previous
//
#include <hip/hip_runtime.h>

typedef unsigned short u16;
typedef short short8 __attribute__((ext_vector_type(8)));
typedef float f32x4 __attribute__((ext_vector_type(4)));

#define MM 18464   // B*N rows
#define NTOK 577

__device__ __forceinline__ u16 f2bf(float f) {
    unsigned u = __builtin_bit_cast(unsigned, f);
    u += 0x7fffu + ((u >> 16) & 1u);
    return (u16)(u >> 16);
}

__device__ __forceinline__ void gload16(const void* g, void* lds) {
    __builtin_amdgcn_global_load_lds(
        (const __attribute__((address_space(1))) unsigned*)g,
        (__attribute__((address_space(3))) unsigned*)lds,
        16, 0, 0);
}

// bijective XCD-chunked remap (m204): consecutive remapped ids share an XCD
__device__ __forceinline__ int xcd_map(int flat, int nwg) {
    const int q = nwg >> 3, r = nwg & 7;
    const int xcd = flat & 7, lid = flat >> 3;
    return (xcd < r ? xcd * (q + 1) : r * (q + 1) + (xcd - r) * q) + lid;
}

__device__ __forceinline__ int2 xcd_swz2(int gx, int gy) {
    const int w = xcd_map(blockIdx.x + blockIdx.y * gx, gx * gy);
    int2 o; o.x = w % gx; o.y = w / gx; return o;
}

// ---------------- weight convert + transpose: src[K][N] f32 -> dst[N][K] bf16 ----------------
__global__ __launch_bounds__(256) void convT(const float* __restrict__ src,
                                             u16* __restrict__ dst, int K, int N) {
    __shared__ float tile[32][33];
    const int k0 = blockIdx.x * 32, n0 = blockIdx.y * 32;
    const int tx = threadIdx.x & 31, ty = threadIdx.x >> 5;  // 32 x 8
#pragma unroll
    for (int i = 0; i < 32; i += 8)
        tile[ty + i][tx] = src[(size_t)(k0 + ty + i) * N + n0 + tx];
    __syncthreads();
#pragma unroll
    for (int i = 0; i < 32; i += 8)
        dst[(size_t)(n0 + ty + i) * K + k0 + tx] = f2bf(tile[tx][ty + i]);
}

// ---------------- layernorm: f32 row[768] -> bf16 ----------------
__global__ __launch_bounds__(192) void ln_k(const float* __restrict__ x,
                                            const float* __restrict__ g,
                                            const float* __restrict__ bt,
                                            u16* __restrict__ out) {
    const int row = blockIdx.x, t = threadIdx.x;
    const float4 v = reinterpret_cast<const float4*>(x + (size_t)row * 768)[t];
    float s = v.x + v.y + v.z + v.w;
    float s2 = v.x * v.x + v.y * v.y + v.z * v.z + v.w * v.w;
#pragma unroll
    for (int off = 32; off > 0; off >>= 1) {
        s += __shfl_down(s, off);
        s2 += __shfl_down(s2, off);
    }
    __shared__ float red[6];
    if ((t & 63) == 0) { red[t >> 6] = s; red[3 + (t >> 6)] = s2; }
    __syncthreads();
    const float S = red[0] + red[1] + red[2];
    const float S2 = red[3] + red[4] + red[5];
    const float mu = S * (1.f / 768.f);
    const float var = S2 * (1.f / 768.f) - mu * mu;
    const float rs = rsqrtf(var + 1e-5f);
    const float4 gg = reinterpret_cast<const float4*>(g)[t];
    const float4 bb = reinterpret_cast<const float4*>(bt)[t];
    ushort4 r;
    r.x = f2bf((v.x - mu) * rs * gg.x + bb.x);
    r.y = f2bf((v.y - mu) * rs * gg.y + bb.y);
    r.z = f2bf((v.z - mu) * rs * gg.z + bb.z);
    r.w = f2bf((v.w - mu) * rs * gg.w + bb.w);
    reinterpret_cast<ushort4*>(out + (size_t)row * 768)[t] = r;
}

// ---------------- GEMM 256x256 tile, BK=64, 8 waves, counted-vmcnt deep pipeline -----------
// C[M][N] = A[M][K](bf16) * BT[N][K](bf16)^T + bias, epilogue per MODE:
// MODE 0: out bf16 = acc + bias                      (qkv)
// MODE 1: out f32  = acc + bias + resid              (proj -> x1)
// MODE 2: out bf16 = gelu(acc + bias)                (fc1)
// MODE 3: out f32  = acc + bias + resid              (fc2 -> d_out)
// LDS tiles [256 rows][8 slots of 16B], slot ^= (row&7); staged linearly via
// global_load_lds with inverse-swizzled per-lane SOURCE (rule #21).
template <int MODE>
__global__ __launch_bounds__(512, 2) void gemm_k(const u16* __restrict__ A,
                                                 const u16* __restrict__ BT,
                                                 const float* __restrict__ bias,
                                                 const float* __restrict__ resid,
                                                 void* __restrict__ outp,
                                                 int M, int N, int K, int mt) {
    __shared__ u16 smem[4][256 * 64];   // A0 B0 A1 B1  (128 KiB)
    const int t = threadIdx.x;
    const int wid = t >> 6, lane = t & 63;
    const int l15 = lane & 15, lg = lane >> 4;
    const int wr = wid >> 2, wc = wid & 3;          // 2M x 4N waves

    const int w = xcd_map(blockIdx.x, gridDim.x);
    const int m0 = (w % mt) * 256, n0 = (w / mt) * 256;

    f32x4 acc[8][4] = {};
    const int NT = K >> 6;

    auto stage = [&](int buf, int k0) {
        u16* Ad = smem[buf * 2];
        u16* Bd = smem[buf * 2 + 1];
#pragma unroll
        for (int i = 0; i < 4; ++i) {
            const int slot = i * 512 + t;
            const int r = slot >> 3, sl = slot & 7;
            const int cs = (sl ^ (r & 7)) << 3;     // inverse-swizzled source chunk
            const size_t dofs = (size_t)(i * 512 + (t & ~63)) * 8;  // wave-uniform
            gload16(A + (size_t)min(m0 + r, M - 1) * K + k0 + cs, Ad + dofs);
            gload16(BT + (size_t)(n0 + r) * K + k0 + cs, Bd + dofs);
        }
    };

    auto compute = [&](int buf) {
        const u16* Ab = smem[buf * 2];
        const u16* Bb = smem[buf * 2 + 1];
#pragma unroll
        for (int half = 0; half < 2; ++half) {
            short8 af[8], bf4[4];
#pragma unroll
            for (int mf = 0; mf < 8; ++mf) {
                const int r = wr * 128 + mf * 16 + l15;
                af[mf] = *(const short8*)&Ab[r * 64 + (((half * 4 + lg) ^ (l15 & 7)) << 3)];
            }
#pragma unroll
            for (int nf = 0; nf < 4; ++nf) {
                const int r = wc * 64 + nf * 16 + l15;
                bf4[nf] = *(const short8*)&Bb[r * 64 + (((half * 4 + lg) ^ (l15 & 7)) << 3)];
            }
            __builtin_amdgcn_s_setprio(1);
#pragma unroll
            for (int mf = 0; mf < 8; ++mf)
#pragma unroll
                for (int nf = 0; nf < 4; ++nf)
                    acc[mf][nf] = __builtin_amdgcn_mfma_f32_16x16x32_bf16(
                        af[mf], bf4[nf], acc[mf][nf], 0, 0, 0);
            __builtin_amdgcn_s_setprio(0);
        }
    };

    // prologue: 2 K-tiles in flight (NT >= 2 for all our shapes)
    stage(0, 0);
    stage(1, 64);
    for (int tt = 0; tt < NT; ++tt) {
        // own tile-tt loads are the oldest; 8 youngest (tile tt+1) may stay in flight
        if (tt < NT - 1) asm volatile("s_waitcnt vmcnt(8)" ::: "memory");
        else             asm volatile("s_waitcnt vmcnt(0)" ::: "memory");
        __builtin_amdgcn_s_barrier();               // all waves' tile-tt loads landed
        __builtin_amdgcn_sched_barrier(0);
        compute(tt & 1);
        __builtin_amdgcn_sched_barrier(0);
        asm volatile("s_waitcnt lgkmcnt(0)" ::: "memory");
        __builtin_amdgcn_s_barrier();               // all waves done reading buf[tt&1]
        __builtin_amdgcn_sched_barrier(0);
        if (tt + 2 < NT) stage(tt & 1, (tt + 2) << 6);
    }

    float bcol[4];
#pragma unroll
    for (int nf = 0; nf < 4; ++nf) bcol[nf] = bias[n0 + wc * 64 + nf * 16 + l15];
#pragma unroll
    for (int mf = 0; mf < 8; ++mf) {
#pragma unroll
        for (int reg = 0; reg < 4; ++reg) {
            const int row = m0 + wr * 128 + mf * 16 + lg * 4 + reg;
            if (row < M) {
#pragma unroll
                for (int nf = 0; nf < 4; ++nf) {
                    const int col = n0 + wc * 64 + nf * 16 + l15;
                    float v = acc[mf][nf][reg] + bcol[nf];
                    if (MODE == 2) v = 0.5f * v * (1.0f + erff(v * 0.70710678118f));
                    if (MODE == 1 || MODE == 3) v += resid[(size_t)row * N + col];
                    if (MODE == 0 || MODE == 2)
                        ((u16*)outp)[(size_t)row * N + col] = f2bf(v);
                    else
                        ((float*)outp)[(size_t)row * N + col] = v;
                }
            }
        }
    }
}

// ---------------- flash attention over qkv[M][2304] bf16, out o[M][768] bf16 ----------------
__global__ __launch_bounds__(256) void attn_k(const u16* __restrict__ qkv,
                                              u16* __restrict__ o) {
    const int2 sw = xcd_swz2(10, 384);
    const int qt = sw.x;             // 0..9
    const int bh = sw.y;             // 0..383
    const int b = bh / 12, h = bh % 12;
    const int t = threadIdx.x, wid = t >> 6, lane = t & 63;
    const int l15 = lane & 15, lg = lane >> 4;
    const size_t base = ((size_t)b * NTOK) * 2304 + (size_t)h * 64;

    __shared__ u16 Ks[64 * 64], VT[64 * 64], Ps[64 * 64];

    int qrow = qt * 64 + wid * 16 + l15;
    qrow = min(qrow, NTOK - 1);
    const u16* Qp = qkv + base + (size_t)qrow * 2304 + lg * 8;
    const short8 qf0 = *(const short8*)(Qp);
    const short8 qf1 = *(const short8*)(Qp + 32);

    f32x4 oacc[4] = {};
    float m_run[4], l_run[4];
#pragma unroll
    for (int j = 0; j < 4; ++j) { m_run[j] = -1e30f; l_run[j] = 0.f; }

    const int srow = t >> 3;               // 0..31 (kv row within half-tile)
    const int cchunk = t & 7;              // 16B chunk within 128B row
    const int ksd = (cchunk ^ (srow & 7)) * 8;   // pre-swizzled K source offset
    u16* ldsK = Ks + wid * 512;
    const int vs0 = ((srow >> 3) ^ cchunk) * 8 + (srow & 7);
    const int vs1 = (((srow >> 3) + 4) ^ cchunk) * 8 + (srow & 7);

    for (int kt = 0; kt < 10; ++kt) {
        const int n0t = kt * 64;
        const int r0 = min(n0t + srow, NTOK - 1);
        const int r1 = min(n0t + srow + 32, NTOK - 1);
        gload16(qkv + base + 768 + (size_t)r0 * 2304 + ksd, ldsK);
        gload16(qkv + base + 768 + (size_t)r1 * 2304 + ksd, ldsK + 2048);
        const short8 v0 = *(const short8*)(qkv + base + 1536 + (size_t)r0 * 2304 + cchunk * 8);
        const short8 v1 = *(const short8*)(qkv + base + 1536 + (size_t)r1 * 2304 + cchunk * 8);
#pragma unroll
        for (int j = 0; j < 8; ++j) {
            VT[(cchunk * 8 + j) * 64 + vs0] = (u16)v0[j];
            VT[(cchunk * 8 + j) * 64 + vs1] = (u16)v1[j];
        }
        __syncthreads();

        // S = Q K^T
        f32x4 s[4];
#pragma unroll
        for (int fc = 0; fc < 4; ++fc) {
            const int krow = fc * 16 + l15;
            const short8 kf0 = *(const short8*)&Ks[krow * 64 + ((lg ^ (krow & 7)) * 8)];
            const short8 kf1 = *(const short8*)&Ks[krow * 64 + (((lg + 4) ^ (krow & 7)) * 8)];
            f32x4 a_ = {};
            a_ = __builtin_amdgcn_mfma_f32_16x16x32_bf16(qf0, kf0, a_, 0, 0, 0);
            a_ = __builtin_amdgcn_mfma_f32_16x16x32_bf16(qf1, kf1, a_, 0, 0, 0);
            s[fc] = a_;
        }
#pragma unroll
        for (int fc = 0; fc < 4; ++fc) {
            const bool valid = (n0t + fc * 16 + l15) < NTOK;
#pragma unroll
            for (int j = 0; j < 4; ++j)
                s[fc][j] = valid ? s[fc][j] * 0.125f : -1e30f;
        }
        float mt_[4];
#pragma unroll
        for (int j = 0; j < 4; ++j)
            mt_[j] = fmaxf(fmaxf(s[0][j], s[1][j]), fmaxf(s[2][j], s[3][j]));
#pragma unroll
        for (int off = 1; off < 16; off <<= 1)
#pragma unroll
            for (int j = 0; j < 4; ++j) mt_[j] = fmaxf(mt_[j], __shfl_xor(mt_[j], off));
        float mn[4], alpha[4];
#pragma unroll
        for (int j = 0; j < 4; ++j) {
            mn[j] = fmaxf(m_run[j], mt_[j]);
            alpha[j] = __expf(m_run[j] - mn[j]);
            m_run[j] = mn[j];
        }
        float lsum[4] = {0.f, 0.f, 0.f, 0.f};
#pragma unroll
        for (int fc = 0; fc < 4; ++fc)
#pragma unroll
            for (int j = 0; j < 4; ++j) {
                const float p = __expf(s[fc][j] - mn[j]);
                s[fc][j] = p;
                lsum[j] += p;
            }
#pragma unroll
        for (int off = 1; off < 16; off <<= 1)
#pragma unroll
            for (int j = 0; j < 4; ++j) lsum[j] += __shfl_xor(lsum[j], off);
#pragma unroll
        for (int j = 0; j < 4; ++j) l_run[j] = l_run[j] * alpha[j] + lsum[j];
#pragma unroll
        for (int fc = 0; fc < 4; ++fc)
#pragma unroll
            for (int j = 0; j < 4; ++j) oacc[fc][j] *= alpha[j];

#pragma unroll
        for (int fc = 0; fc < 4; ++fc)
#pragma unroll
            for (int j = 0; j < 4; ++j) {
                const int q = wid * 16 + lg * 4 + j;
                Ps[q * 64 + (((fc * 2 + (l15 >> 3)) ^ (q & 7)) * 8) + (l15 & 7)] =
                    f2bf(s[fc][j]);
            }
        asm volatile("s_waitcnt lgkmcnt(0)" ::: "memory");

#pragma unroll
        for (int c = 0; c < 2; ++c) {
            const short8 pf = *(const short8*)
                &Ps[(wid * 16 + l15) * 64 + (((c * 4 + lg) ^ (l15 & 7)) * 8)];
#pragma unroll
            for (int fc = 0; fc < 4; ++fc) {
                const short8 vf = *(const short8*)
                    &VT[(fc * 16 + l15) * 64 +
                        (((c * 4 + lg) ^ (fc * 2 + (l15 >> 3))) * 8)];
                oacc[fc] = __builtin_amdgcn_mfma_f32_16x16x32_bf16(pf, vf, oacc[fc], 0, 0, 0);
            }
        }
        __syncthreads();
    }

#pragma unroll
    for (int j = 0; j < 4; ++j) {
        const int row = qt * 64 + wid * 16 + lg * 4 + j;
        if (row < NTOK) {
            const float inv = 1.0f / l_run[j];
#pragma unroll
            for (int fc = 0; fc < 4; ++fc)
                o[((size_t)(b * NTOK + row)) * 768 + h * 64 + fc * 16 + l15] =
                    f2bf(oacc[fc][j] * inv);
        }
    }
}

extern "C" void kernel_launch(void* const* d_in, const int* in_sizes, int n_in,
                              void* d_out, int out_size, void* d_ws, size_t ws_size,
                              hipStream_t stream) {
    const float* x      = (const float*)d_in[0];
    const float* ln1_g  = (const float*)d_in[1];
    const float* ln1_b  = (const float*)d_in[2];
    const float* qkv_w  = (const float*)d_in[3];
    const float* qkv_b  = (const float*)d_in[4];
    const float* proj_w = (const float*)d_in[5];
    const float* proj_b = (const float*)d_in[6];
    const float* ln2_g  = (const float*)d_in[7];
    const float* ln2_b  = (const float*)d_in[8];
    const float* fc1_w  = (const float*)d_in[9];
    const float* fc1_b  = (const float*)d_in[10];
    const float* fc2_w  = (const float*)d_in[11];
    const float* fc2_b  = (const float*)d_in[12];
    float* out = (float*)d_out;

    char* ws = (char*)d_ws;
    size_t off = 0;
    u16* WQ  = (u16*)(ws + off); off += (size_t)2304 * 768 * 2;   // qkv_w^T
    u16* WP  = (u16*)(ws + off); off += (size_t)768 * 768 * 2;    // proj_w^T
    u16* W1  = (u16*)(ws + off); off += (size_t)3072 * 768 * 2;   // fc1_w^T
    u16* W2  = (u16*)(ws + off); off += (size_t)768 * 3072 * 2;   // fc2_w^T
    u16* LN1 = (u16*)(ws + off); off += (size_t)MM * 768 * 2;
    u16* QKV = (u16*)(ws + off); off += (size_t)MM * 2304 * 2;
    u16* OB  = (u16*)(ws + off); off += (size_t)MM * 768 * 2;
    float* X1 = (float*)(ws + off); off += (size_t)MM * 768 * 4;
    u16* LN2 = (u16*)(ws + off); off += (size_t)MM * 768 * 2;
    u16* HID = LN1;  // aliases LN1+QKV (dead by fc1)

    // weights -> bf16 transposed
    convT<<<dim3(24, 72), 256, 0, stream>>>(qkv_w, WQ, 768, 2304);
    convT<<<dim3(24, 24), 256, 0, stream>>>(proj_w, WP, 768, 768);
    convT<<<dim3(24, 96), 256, 0, stream>>>(fc1_w, W1, 768, 3072);
    convT<<<dim3(96, 24), 256, 0, stream>>>(fc2_w, W2, 3072, 768);

    const int mt = (MM + 255) / 256;   // 73 row tiles
    // MSA branch
    ln_k<<<MM, 192, 0, stream>>>(x, ln1_g, ln1_b, LN1);
    gemm_k<0><<<mt * 9, 512, 0, stream>>>(LN1, WQ, qkv_b, nullptr, QKV,
                                          MM, 2304, 768, mt);
    attn_k<<<dim3(10, 384), 256, 0, stream>>>(QKV, OB);
    gemm_k<1><<<mt * 3, 512, 0, stream>>>(OB, WP, proj_b, x, X1,
                                          MM, 768, 768, mt);
    // MLP branch
    ln_k<<<MM, 192, 0, stream>>>(X1, ln2_g, ln2_b, LN2);
    gemm_k<2><<<mt * 12, 512, 0, stream>>>(LN2, W1, fc1_b, nullptr, HID,
                                           MM, 3072, 768, mt);
    gemm_k<3><<<mt * 3, 512, 0, stream>>>(HID, W2, fc2_b, X1, out,
                                          MM, 768, 3072, mt);
}

// Round 4
// 741.616 us; speedup vs baseline: 1.2026x; 1.0107x over previous
//
#include <hip/hip_runtime.h>

typedef unsigned short u16;
typedef short short8 __attribute__((ext_vector_type(8)));
typedef float f32x4 __attribute__((ext_vector_type(4)));

#define MM 18464   // B*N rows
#define NTOK 577

__device__ __forceinline__ u16 f2bf(float f) {
    unsigned u = __builtin_bit_cast(unsigned, f);
    u += 0x7fffu + ((u >> 16) & 1u);
    return (u16)(u >> 16);
}

__device__ __forceinline__ void gload16(const void* g, void* lds) {
    __builtin_amdgcn_global_load_lds(
        (const __attribute__((address_space(1))) unsigned*)g,
        (__attribute__((address_space(3))) unsigned*)lds,
        16, 0, 0);
}

// bijective XCD-chunked remap (m204): consecutive remapped ids share an XCD
__device__ __forceinline__ int xcd_map(int flat, int nwg) {
    const int q = nwg >> 3, r = nwg & 7;
    const int xcd = flat & 7, lid = flat >> 3;
    return (xcd < r ? xcd * (q + 1) : r * (q + 1) + (xcd - r) * q) + lid;
}

__device__ __forceinline__ int2 xcd_swz2(int gx, int gy) {
    const int w = xcd_map(blockIdx.x + blockIdx.y * gx, gx * gy);
    int2 o; o.x = w % gx; o.y = w / gx; return o;
}

// ---------------- weight convert + transpose: src[K][N] f32 -> dst[N][K] bf16 ----------------
__global__ __launch_bounds__(256) void convT(const float* __restrict__ src,
                                             u16* __restrict__ dst, int K, int N) {
    __shared__ float tile[32][33];
    const int k0 = blockIdx.x * 32, n0 = blockIdx.y * 32;
    const int tx = threadIdx.x & 31, ty = threadIdx.x >> 5;  // 32 x 8
#pragma unroll
    for (int i = 0; i < 32; i += 8)
        tile[ty + i][tx] = src[(size_t)(k0 + ty + i) * N + n0 + tx];
    __syncthreads();
#pragma unroll
    for (int i = 0; i < 32; i += 8)
        dst[(size_t)(n0 + ty + i) * K + k0 + tx] = f2bf(tile[tx][ty + i]);
}

// ---------------- layernorm: f32 row[768] -> bf16 ----------------
__global__ __launch_bounds__(192) void ln_k(const float* __restrict__ x,
                                            const float* __restrict__ g,
                                            const float* __restrict__ bt,
                                            u16* __restrict__ out) {
    const int row = blockIdx.x, t = threadIdx.x;
    const float4 v = reinterpret_cast<const float4*>(x + (size_t)row * 768)[t];
    float s = v.x + v.y + v.z + v.w;
    float s2 = v.x * v.x + v.y * v.y + v.z * v.z + v.w * v.w;
#pragma unroll
    for (int off = 32; off > 0; off >>= 1) {
        s += __shfl_down(s, off);
        s2 += __shfl_down(s2, off);
    }
    __shared__ float red[6];
    if ((t & 63) == 0) { red[t >> 6] = s; red[3 + (t >> 6)] = s2; }
    __syncthreads();
    const float S = red[0] + red[1] + red[2];
    const float S2 = red[3] + red[4] + red[5];
    const float mu = S * (1.f / 768.f);
    const float var = S2 * (1.f / 768.f) - mu * mu;
    const float rs = rsqrtf(var + 1e-5f);
    const float4 gg = reinterpret_cast<const float4*>(g)[t];
    const float4 bb = reinterpret_cast<const float4*>(bt)[t];
    ushort4 r;
    r.x = f2bf((v.x - mu) * rs * gg.x + bb.x);
    r.y = f2bf((v.y - mu) * rs * gg.y + bb.y);
    r.z = f2bf((v.z - mu) * rs * gg.z + bb.z);
    r.w = f2bf((v.w - mu) * rs * gg.w + bb.w);
    reinterpret_cast<ushort4*>(out + (size_t)row * 768)[t] = r;
}

// ---------------- GEMM 256x256, BK=64, 8 waves, 4-phase counted-vmcnt pipeline -------------
// C[M][N] = A[M][K](bf16) * BT[N][K](bf16)^T + bias, epilogue per MODE:
// MODE 0: out bf16 = acc + bias                      (qkv)
// MODE 1: out f32  = acc + bias + resid              (proj -> x1)
// MODE 2: out bf16 = gelu(acc + bias)                (fc1)
// MODE 3: out f32  = acc + bias + resid              (fc2 -> d_out)
// LDS: [dbuf][mat A/B][kh][256 rows][4 chunks x 16B], chunk ^= (r>>1)&3 (2-way = free).
// Stage order per tile tt (targets idle buf): Ak0@p0 Bk0@p1 Ak1@p2 Bk1@p3.
// vmcnt(4) at p1-end drains tile-tt's k1 halves; at p3-end drains tile-tt+1's k0 halves.
// MFMA operands SWAPPED (bf,af) so lane holds 4 consecutive cols -> vector epilogue.
template <int MODE>
__global__ __launch_bounds__(512, 2) void gemm_k(const u16* __restrict__ A,
                                                 const u16* __restrict__ BT,
                                                 const float* __restrict__ bias,
                                                 const float* __restrict__ resid,
                                                 void* __restrict__ outp,
                                                 int M, int N, int K, int mt) {
    __shared__ u16 smem[65536];   // 128 KiB: plane(buf,mat,kh) = ((buf*2+mat)*2+kh)*8192
    const int t = threadIdx.x;
    const int wid = t >> 6, lane = t & 63;
    const int l15 = lane & 15, lg = lane >> 4;
    const int wr = wid >> 2, wc = wid & 3;          // 2M x 4N waves
    const int w = xcd_map(blockIdx.x, gridDim.x);
    const int m0 = (w % mt) * 256, n0 = (w / mt) * 256;
    const int swz = (l15 >> 1) & 3;

    f32x4 acc[8][4] = {};
    const int NT = K >> 6;

    auto stage = [&](int buf, int kt, int mat, int kh) {
        u16* plane = smem + (size_t)(((buf << 1) | mat) * 2 + kh) * 8192;
        const u16* src = mat ? BT : A;
        const int rbase = mat ? n0 : m0;
        const int kk = kt * 64 + kh * 32;
#pragma unroll
        for (int i = 0; i < 2; ++i) {
            const int flat = i * 512 + t;
            const int r = flat >> 2, c = flat & 3;
            const int scol = (c ^ ((r >> 1) & 3)) << 3;
            int grow = rbase + r;
            if (mat == 0) grow = min(grow, M - 1);
            gload16(src + (size_t)grow * K + kk + scol,
                    plane + (size_t)(i * 512 + (t & ~63)) * 8);
        }
    };

    short8 bfv[4];
    auto read_bf = [&](int buf, int kh) {
        const u16* plane = smem + (size_t)((buf << 1 | 1) * 2 + kh) * 8192;
        const int rb = wc * 64 + l15;
#pragma unroll
        for (int nf = 0; nf < 4; ++nf)
            bfv[nf] = *(const short8*)&plane[(rb + nf * 16) * 32 + ((lg ^ swz) << 3)];
    };
    auto phase = [&](int buf, int mh, int kh, bool loadB,
                     int stMat, int stKh, int kt1, bool doStage, int vm) {
        if (loadB) read_bf(buf, kh);
        short8 afv[4];
        {
            const u16* plane = smem + (size_t)((buf << 1) * 2 + kh) * 8192;
            const int rb = wr * 128 + mh * 64 + l15;
#pragma unroll
            for (int mf = 0; mf < 4; ++mf)
                afv[mf] = *(const short8*)&plane[(rb + mf * 16) * 32 + ((lg ^ swz) << 3)];
        }
        if (doStage) stage(buf ^ 1, kt1, stMat, stKh);
        __builtin_amdgcn_s_barrier();
        asm volatile("s_waitcnt lgkmcnt(0)" ::: "memory");
        __builtin_amdgcn_sched_barrier(0);
        __builtin_amdgcn_s_setprio(1);
#pragma unroll
        for (int mf = 0; mf < 4; ++mf)
#pragma unroll
            for (int nf = 0; nf < 4; ++nf)
                acc[mh * 4 + mf][nf] = __builtin_amdgcn_mfma_f32_16x16x32_bf16(
                    bfv[nf], afv[mf], acc[mh * 4 + mf][nf], 0, 0, 0);
        __builtin_amdgcn_s_setprio(0);
        if (vm == 4)      asm volatile("s_waitcnt vmcnt(4)" ::: "memory");
        else if (vm == 0) asm volatile("s_waitcnt vmcnt(0)" ::: "memory");
        __builtin_amdgcn_s_barrier();
        __builtin_amdgcn_sched_barrier(0);
    };

    // prologue: tile 0 fully staged; k0 halves drained, k1 halves left in flight
    stage(0, 0, 0, 0); stage(0, 0, 1, 0); stage(0, 0, 0, 1); stage(0, 0, 1, 1);
    asm volatile("s_waitcnt vmcnt(4)" ::: "memory");
    __builtin_amdgcn_s_barrier();
    __builtin_amdgcn_sched_barrier(0);

    int buf = 0;
    for (int tt = 0; tt < NT; ++tt) {
        const bool pre = (tt + 1 < NT);
        phase(buf, 0, 0, true,  0, 0, tt + 1, pre, -1);
        phase(buf, 1, 0, false, 1, 0, tt + 1, pre, pre ? 4 : 0);
        phase(buf, 0, 1, true,  0, 1, tt + 1, pre, -1);
        phase(buf, 1, 1, false, 1, 1, tt + 1, pre, pre ? 4 : -1);
        buf ^= 1;
    }

    // epilogue: lane holds rows mf*16+l15, cols nf*16+lg*4+{0..3}  (operand-swap layout)
    float4 bb4[4];
#pragma unroll
    for (int nf = 0; nf < 4; ++nf)
        bb4[nf] = *(const float4*)&bias[n0 + wc * 64 + nf * 16 + lg * 4];
#pragma unroll
    for (int mf = 0; mf < 8; ++mf) {
        const int row = m0 + wr * 128 + mf * 16 + l15;
        if (row < M) {
#pragma unroll
            for (int nf = 0; nf < 4; ++nf) {
                const int col = n0 + wc * 64 + nf * 16 + lg * 4;
                float v0 = acc[mf][nf][0] + bb4[nf].x;
                float v1 = acc[mf][nf][1] + bb4[nf].y;
                float v2 = acc[mf][nf][2] + bb4[nf].z;
                float v3 = acc[mf][nf][3] + bb4[nf].w;
                if (MODE == 2) {
                    v0 = 0.5f * v0 * (1.0f + erff(v0 * 0.70710678118f));
                    v1 = 0.5f * v1 * (1.0f + erff(v1 * 0.70710678118f));
                    v2 = 0.5f * v2 * (1.0f + erff(v2 * 0.70710678118f));
                    v3 = 0.5f * v3 * (1.0f + erff(v3 * 0.70710678118f));
                }
                if (MODE == 1 || MODE == 3) {
                    const float4 rr = *(const float4*)&resid[(size_t)row * N + col];
                    v0 += rr.x; v1 += rr.y; v2 += rr.z; v3 += rr.w;
                }
                if (MODE == 0 || MODE == 2) {
                    ushort4 r4;
                    r4.x = f2bf(v0); r4.y = f2bf(v1); r4.z = f2bf(v2); r4.w = f2bf(v3);
                    *(ushort4*)&((u16*)outp)[(size_t)row * N + col] = r4;
                } else {
                    float4 f4; f4.x = v0; f4.y = v1; f4.z = v2; f4.w = v3;
                    *(float4*)&((float*)outp)[(size_t)row * N + col] = f4;
                }
            }
        }
    }
}

// ---------------- flash attention over qkv[M][2304] bf16, out o[M][768] bf16 ----------------
__global__ __launch_bounds__(256) void attn_k(const u16* __restrict__ qkv,
                                              u16* __restrict__ o) {
    const int2 sw = xcd_swz2(10, 384);
    const int qt = sw.x;             // 0..9
    const int bh = sw.y;             // 0..383
    const int b = bh / 12, h = bh % 12;
    const int t = threadIdx.x, wid = t >> 6, lane = t & 63;
    const int l15 = lane & 15, lg = lane >> 4;
    const size_t base = ((size_t)b * NTOK) * 2304 + (size_t)h * 64;

    __shared__ u16 Ks[64 * 64], VT[64 * 64], Ps[64 * 64];

    int qrow = qt * 64 + wid * 16 + l15;
    qrow = min(qrow, NTOK - 1);
    const u16* Qp = qkv + base + (size_t)qrow * 2304 + lg * 8;
    const short8 qf0 = *(const short8*)(Qp);
    const short8 qf1 = *(const short8*)(Qp + 32);

    f32x4 oacc[4] = {};
    float m_run[4], l_run[4];
#pragma unroll
    for (int j = 0; j < 4; ++j) { m_run[j] = -1e30f; l_run[j] = 0.f; }

    const int srow = t >> 3;               // 0..31 (kv row within half-tile)
    const int cchunk = t & 7;              // 16B chunk within 128B row
    const int ksd = (cchunk ^ (srow & 7)) * 8;   // pre-swizzled K source offset
    u16* ldsK = Ks + wid * 512;
    const int vs0 = ((srow >> 3) ^ cchunk) * 8 + (srow & 7);
    const int vs1 = (((srow >> 3) + 4) ^ cchunk) * 8 + (srow & 7);

    for (int kt = 0; kt < 10; ++kt) {
        const int n0t = kt * 64;
        const int r0 = min(n0t + srow, NTOK - 1);
        const int r1 = min(n0t + srow + 32, NTOK - 1);
        gload16(qkv + base + 768 + (size_t)r0 * 2304 + ksd, ldsK);
        gload16(qkv + base + 768 + (size_t)r1 * 2304 + ksd, ldsK + 2048);
        const short8 v0 = *(const short8*)(qkv + base + 1536 + (size_t)r0 * 2304 + cchunk * 8);
        const short8 v1 = *(const short8*)(qkv + base + 1536 + (size_t)r1 * 2304 + cchunk * 8);
#pragma unroll
        for (int j = 0; j < 8; ++j) {
            VT[(cchunk * 8 + j) * 64 + vs0] = (u16)v0[j];
            VT[(cchunk * 8 + j) * 64 + vs1] = (u16)v1[j];
        }
        __syncthreads();

        // S = Q K^T
        f32x4 s[4];
#pragma unroll
        for (int fc = 0; fc < 4; ++fc) {
            const int krow = fc * 16 + l15;
            const short8 kf0 = *(const short8*)&Ks[krow * 64 + ((lg ^ (krow & 7)) * 8)];
            const short8 kf1 = *(const short8*)&Ks[krow * 64 + (((lg + 4) ^ (krow & 7)) * 8)];
            f32x4 a_ = {};
            a_ = __builtin_amdgcn_mfma_f32_16x16x32_bf16(qf0, kf0, a_, 0, 0, 0);
            a_ = __builtin_amdgcn_mfma_f32_16x16x32_bf16(qf1, kf1, a_, 0, 0, 0);
            s[fc] = a_;
        }
#pragma unroll
        for (int fc = 0; fc < 4; ++fc) {
            const bool valid = (n0t + fc * 16 + l15) < NTOK;
#pragma unroll
            for (int j = 0; j < 4; ++j)
                s[fc][j] = valid ? s[fc][j] * 0.125f : -1e30f;
        }
        float mt_[4];
#pragma unroll
        for (int j = 0; j < 4; ++j)
            mt_[j] = fmaxf(fmaxf(s[0][j], s[1][j]), fmaxf(s[2][j], s[3][j]));
#pragma unroll
        for (int off = 1; off < 16; off <<= 1)
#pragma unroll
            for (int j = 0; j < 4; ++j) mt_[j] = fmaxf(mt_[j], __shfl_xor(mt_[j], off));
        float mn[4], alpha[4];
#pragma unroll
        for (int j = 0; j < 4; ++j) {
            mn[j] = fmaxf(m_run[j], mt_[j]);
            alpha[j] = __expf(m_run[j] - mn[j]);
            m_run[j] = mn[j];
        }
        float lsum[4] = {0.f, 0.f, 0.f, 0.f};
#pragma unroll
        for (int fc = 0; fc < 4; ++fc)
#pragma unroll
            for (int j = 0; j < 4; ++j) {
                const float p = __expf(s[fc][j] - mn[j]);
                s[fc][j] = p;
                lsum[j] += p;
            }
#pragma unroll
        for (int off = 1; off < 16; off <<= 1)
#pragma unroll
            for (int j = 0; j < 4; ++j) lsum[j] += __shfl_xor(lsum[j], off);
#pragma unroll
        for (int j = 0; j < 4; ++j) l_run[j] = l_run[j] * alpha[j] + lsum[j];
#pragma unroll
        for (int fc = 0; fc < 4; ++fc)
#pragma unroll
            for (int j = 0; j < 4; ++j) oacc[fc][j] *= alpha[j];

#pragma unroll
        for (int fc = 0; fc < 4; ++fc)
#pragma unroll
            for (int j = 0; j < 4; ++j) {
                const int q = wid * 16 + lg * 4 + j;
                Ps[q * 64 + (((fc * 2 + (l15 >> 3)) ^ (q & 7)) * 8) + (l15 & 7)] =
                    f2bf(s[fc][j]);
            }
        asm volatile("s_waitcnt lgkmcnt(0)" ::: "memory");

#pragma unroll
        for (int c = 0; c < 2; ++c) {
            const short8 pf = *(const short8*)
                &Ps[(wid * 16 + l15) * 64 + (((c * 4 + lg) ^ (l15 & 7)) * 8)];
#pragma unroll
            for (int fc = 0; fc < 4; ++fc) {
                const short8 vf = *(const short8*)
                    &VT[(fc * 16 + l15) * 64 +
                        (((c * 4 + lg) ^ (fc * 2 + (l15 >> 3))) * 8)];
                oacc[fc] = __builtin_amdgcn_mfma_f32_16x16x32_bf16(pf, vf, oacc[fc], 0, 0, 0);
            }
        }
        __syncthreads();
    }

#pragma unroll
    for (int j = 0; j < 4; ++j) {
        const int row = qt * 64 + wid * 16 + lg * 4 + j;
        if (row < NTOK) {
            const float inv = 1.0f / l_run[j];
#pragma unroll
            for (int fc = 0; fc < 4; ++fc)
                o[((size_t)(b * NTOK + row)) * 768 + h * 64 + fc * 16 + l15] =
                    f2bf(oacc[fc][j] * inv);
        }
    }
}

extern "C" void kernel_launch(void* const* d_in, const int* in_sizes, int n_in,
                              void* d_out, int out_size, void* d_ws, size_t ws_size,
                              hipStream_t stream) {
    const float* x      = (const float*)d_in[0];
    const float* ln1_g  = (const float*)d_in[1];
    const float* ln1_b  = (const float*)d_in[2];
    const float* qkv_w  = (const float*)d_in[3];
    const float* qkv_b  = (const float*)d_in[4];
    const float* proj_w = (const float*)d_in[5];
    const float* proj_b = (const float*)d_in[6];
    const float* ln2_g  = (const float*)d_in[7];
    const float* ln2_b  = (const float*)d_in[8];
    const float* fc1_w  = (const float*)d_in[9];
    const float* fc1_b  = (const float*)d_in[10];
    const float* fc2_w  = (const float*)d_in[11];
    const float* fc2_b  = (const float*)d_in[12];
    float* out = (float*)d_out;

    char* ws = (char*)d_ws;
    size_t off = 0;
    u16* WQ  = (u16*)(ws + off); off += (size_t)2304 * 768 * 2;   // qkv_w^T
    u16* WP  = (u16*)(ws + off); off += (size_t)768 * 768 * 2;    // proj_w^T
    u16* W1  = (u16*)(ws + off); off += (size_t)3072 * 768 * 2;   // fc1_w^T
    u16* W2  = (u16*)(ws + off); off += (size_t)768 * 3072 * 2;   // fc2_w^T
    u16* LN1 = (u16*)(ws + off); off += (size_t)MM * 768 * 2;
    u16* QKV = (u16*)(ws + off); off += (size_t)MM * 2304 * 2;
    u16* OB  = (u16*)(ws + off); off += (size_t)MM * 768 * 2;
    float* X1 = (float*)(ws + off); off += (size_t)MM * 768 * 4;
    u16* LN2 = (u16*)(ws + off); off += (size_t)MM * 768 * 2;
    u16* HID = LN1;  // aliases LN1+QKV (dead by fc1)

    // weights -> bf16 transposed
    convT<<<dim3(24, 72), 256, 0, stream>>>(qkv_w, WQ, 768, 2304);
    convT<<<dim3(24, 24), 256, 0, stream>>>(proj_w, WP, 768, 768);
    convT<<<dim3(24, 96), 256, 0, stream>>>(fc1_w, W1, 768, 3072);
    convT<<<dim3(96, 24), 256, 0, stream>>>(fc2_w, W2, 3072, 768);

    const int mt = (MM + 255) / 256;   // 73 row tiles
    // MSA branch
    ln_k<<<MM, 192, 0, stream>>>(x, ln1_g, ln1_b, LN1);
    gemm_k<0><<<mt * 9, 512, 0, stream>>>(LN1, WQ, qkv_b, nullptr, QKV,
                                          MM, 2304, 768, mt);
    attn_k<<<dim3(10, 384), 256, 0, stream>>>(QKV, OB);
    gemm_k<1><<<mt * 3, 512, 0, stream>>>(OB, WP, proj_b, x, X1,
                                          MM, 768, 768, mt);
    // MLP branch
    ln_k<<<MM, 192, 0, stream>>>(X1, ln2_g, ln2_b, LN2);
    gemm_k<2><<<mt * 12, 512, 0, stream>>>(LN2, W1, fc1_b, nullptr, HID,
                                           MM, 3072, 768, mt);
    gemm_k<3><<<mt * 3, 512, 0, stream>>>(HID, W2, fc2_b, X1, out,
                                          MM, 768, 3072, mt);
}